// Round 5
// baseline (463.752 us; speedup 1.0000x reference)
//
#include <hip/hip_runtime.h>
#include <hip/hip_bf16.h>
#include <hip/hip_fp16.h>
#include <math.h>

typedef __hip_bfloat16 bf16;
typedef __attribute__((ext_vector_type(8))) short short8;
typedef __attribute__((ext_vector_type(4))) float f32x4;

__device__ __forceinline__ float elu_f(float x){ return x > 0.f ? x : expm1f(x); }
__device__ __forceinline__ float b2f(unsigned short u){ return __uint_as_float(((unsigned)u) << 16); }
__device__ __forceinline__ unsigned short f2b(float f){ bf16 h = __float2bfloat16(f); return *reinterpret_cast<unsigned short*>(&h); }
__device__ __forceinline__ float2 h2f2(unsigned u){
    __half2 h = *reinterpret_cast<__half2*>(&u);
    return make_float2(__low2float(h), __high2float(h));
}

// ---------- dtype detection (parallel) + counts zeroing (folded) ----------
__global__ __launch_bounds__(256) void detect_part_kernel(const unsigned* __restrict__ ei_u, int twoE_words,
                                                          const unsigned* __restrict__ x_u, int min_xwords,
                                                          int* __restrict__ raw,
                                                          int* __restrict__ counts, int N){
    __shared__ int sd[256];
    __shared__ int sc[256];
    int tid = threadIdx.x;
    int gid = blockIdx.x*256 + tid;
    long long pairs = twoE_words/2;

    // folded: zero the counts array (saves a hipMemsetAsync dispatch)
    for (int i2 = gid; i2 < N; i2 += 32768) counts[i2] = 0;

    int orv = 0;
    if (gid < 16384 && pairs > 0){
        long long idx = ((long long)gid * pairs) / 16384;
        long long w = 2*idx + 1;
        if (w < twoE_words) orv = (int)ei_u[w];
    }
    int cnt = 0;
    int s = gid - 16384;
    if (s >= 0 && s < 4096){
        long long idx = ((long long)s * min_xwords) / 4096;
        if (idx < min_xwords){
            unsigned e = (x_u[idx] >> 7) & 0xFFu;
            cnt = (e >= 96u && e <= 160u) ? 1 : 0;
        }
    }
    sd[tid] = orv; sc[tid] = cnt;
    __syncthreads();
    #pragma unroll
    for (int off = 128; off > 0; off >>= 1){
        if (tid < off){ sd[tid] |= sd[tid+off]; sc[tid] += sc[tid+off]; }
        __syncthreads();
    }
    if (tid == 0){
        if (sd[0]) atomicOr(&raw[0], sd[0]);
        if (sc[0]) atomicAdd(&raw[1], sc[0]);
    }
}

__global__ void finalize_kernel(const int* __restrict__ raw, int* __restrict__ flags){
    flags[0] = (raw[0] == 0) ? 1 : 0;
    flags[1] = (raw[1]*2 > 4096) ? 1 : 0;
}

__device__ __forceinline__ int load_src(const int* ei, int e, int E, int is64){
    return is64 ? ei[2*e] : ei[e];
}
__device__ __forceinline__ int load_dst(const int* ei, int e, int E, int is64){
    return is64 ? ei[2*(E + e)] : ei[E + e];
}
__device__ __forceinline__ float loadf(const void* base, size_t idx, int isbf){
    return isbf ? __bfloat162float(((const bf16*)base)[idx]) : ((const float*)base)[idx];
}

// ---------- CSR build ----------
__global__ void count_kernel(const int* __restrict__ ei, const int* __restrict__ flags,
                             int* __restrict__ counts, int E, int N){
    int e = blockIdx.x*256 + threadIdx.x;
    if (e < E){
        int d = load_dst(ei, e, E, flags[0]);
        if ((unsigned)d < (unsigned)N) atomicAdd(&counts[d], 1);
    }
}

__global__ void partial_kernel(const int* __restrict__ counts, int* __restrict__ partial, int N){
    __shared__ int sd[256];
    int tid = threadIdx.x;
    int i = blockIdx.x*256 + tid;
    sd[tid] = (i < N) ? counts[i] : 0;
    __syncthreads();
    #pragma unroll
    for (int off = 128; off > 0; off >>= 1){
        if (tid < off) sd[tid] += sd[tid+off];
        __syncthreads();
    }
    if (tid == 0) partial[blockIdx.x] = sd[0];
}

__global__ void scanp_kernel(const int* __restrict__ partial, int* __restrict__ blockoff, int nb){
    __shared__ int sd[256];
    int tid = threadIdx.x;
    int v = (tid < nb) ? partial[tid] : 0;
    sd[tid] = v;
    __syncthreads();
    #pragma unroll
    for (int off = 1; off < 256; off <<= 1){
        int t = (tid >= off) ? sd[tid-off] : 0;
        __syncthreads();
        sd[tid] += t;
        __syncthreads();
    }
    if (tid < nb) blockoff[tid] = sd[tid] - v;
}

// offsets + cursor + dinv (fused)
__global__ void offsets_kernel(const int* __restrict__ counts, const int* __restrict__ blockoff,
                               int* __restrict__ offsets, int* __restrict__ cursor,
                               float* __restrict__ dinv, int N){
    __shared__ int sd[256];
    int tid = threadIdx.x;
    int i = blockIdx.x*256 + tid;
    int v = (i < N) ? counts[i] : 0;
    sd[tid] = v;
    __syncthreads();
    #pragma unroll
    for (int off = 1; off < 256; off <<= 1){
        int t = (tid >= off) ? sd[tid-off] : 0;
        __syncthreads();
        sd[tid] += t;
        __syncthreads();
    }
    if (i < N){
        int o = blockoff[blockIdx.x] + sd[tid] - v;
        offsets[i] = o;
        cursor[i]  = o;
        double d = (double)(v + 1);
        if (d < 1.0) d = 1.0;
        dinv[i] = (float)(1.0 / sqrt(d));
    }
}

__global__ void scatter_kernel(const int* __restrict__ ei, const int* __restrict__ flags,
                               int* __restrict__ cursor, int* __restrict__ csr, int E, int N){
    int e = blockIdx.x*256 + threadIdx.x;
    if (e < E){
        int is64 = flags[0];
        int d = load_dst(ei, e, E, is64);
        int s = load_src(ei, e, E, is64);
        if ((unsigned)d < (unsigned)N){
            int pos = atomicAdd(&cursor[d], 1);
            if ((unsigned)pos < (unsigned)E) csr[pos] = s;
        }
    }
}

// ---------- W prep: W^T split into bf16 hi/lo. 256 blocks; thread = one output element ----------
__global__ __launch_bounds__(256) void wprep_kernel(const void* __restrict__ W0, const void* __restrict__ W1,
                                                    const void* __restrict__ W2, const void* __restrict__ W3,
                                                    const int* __restrict__ flags,
                                                    unsigned short* __restrict__ WThi, unsigned short* __restrict__ WTlo){
    int l = blockIdx.x >> 6;
    const void* Wl = l == 0 ? W0 : l == 1 ? W1 : l == 2 ? W2 : W3;
    int isbf = flags[1];
    int o = (blockIdx.x & 63)*256 + threadIdx.x;   // o = c*128 + k
    int c = o >> 7, k = o & 127;
    unsigned short hi, lo;
    if (isbf){
        hi = ((const unsigned short*)Wl)[k*128 + c]; lo = 0;
    } else {
        float w = ((const float*)Wl)[k*128 + c];
        hi = f2b(w);
        lo = f2b(w - b2f(hi));
    }
    WThi[(size_t)l*16384 + o] = hi;
    WTlo[(size_t)l*16384 + o] = lo;
}

// ---------- GEMM: XW[N,128] = X[N,128] @ W[128,128] on matrix cores; OUTPUT ALWAYS fp16.
// W fragments read DIRECTLY from global (64KB, L1/L2-hot, reused by all blocks) -> no b-tile
// LDS, single barrier. fp32 path: bf16x2 split (hi/lo), 3 MFMA passes. bf16: single pass.
// Fragment recipe (verified m92/m97): row-major A + B^T; lane reads row (lane&15),
// 8 contiguous k at 8*(lane>>4); C/D: col=lane&15, row=4*(lane>>4)+reg.
__global__ __launch_bounds__(256) void gemm_kernel(const void* __restrict__ X,
                                                   const unsigned short* __restrict__ WThi,
                                                   const unsigned short* __restrict__ WTlo,
                                                   const int* __restrict__ flags,
                                                   __half* __restrict__ Y, int N){
    __shared__ __align__(16) unsigned short xhi[64*136];
    __shared__ __align__(16) unsigned short xlo[64*136];
    int tid = threadIdx.x;
    int r0 = blockIdx.x*64;
    int isbf = flags[1];

    if (isbf){
        for (int i = tid; i < 64*16; i += 256){
            int r = i >> 4, sg = i & 15;
            float4 v = make_float4(0.f,0.f,0.f,0.f);
            if (r0 + r < N) v = ((const float4*)X)[(size_t)(r0+r)*16 + sg];
            *(float4*)&xhi[r*136 + sg*8] = v;
        }
    } else {
        for (int i = tid; i < 64*32; i += 256){
            int r = i >> 5, f4 = i & 31;
            float4 v = make_float4(0.f,0.f,0.f,0.f);
            if (r0 + r < N) v = ((const float4*)X)[(size_t)(r0+r)*32 + f4];
            ushort4 hv, lv;
            hv.x = f2b(v.x); lv.x = f2b(v.x - b2f(hv.x));
            hv.y = f2b(v.y); lv.y = f2b(v.y - b2f(hv.y));
            hv.z = f2b(v.z); lv.z = f2b(v.z - b2f(hv.z));
            hv.w = f2b(v.w); lv.w = f2b(v.w - b2f(hv.w));
            *(ushort4*)&xhi[r*136 + f4*4] = hv;
            *(ushort4*)&xlo[r*136 + f4*4] = lv;
        }
    }
    __syncthreads();

    int wv = tid >> 6, lane = tid & 63;
    int lq = lane & 15, lh = lane >> 4;
    const unsigned short* arow = &xhi[(wv*16 + lq)*136 + lh*8];
    const unsigned short* lrow = &xlo[(wv*16 + lq)*136 + lh*8];
    const unsigned short* wbh  = WThi + lq*128 + lh*8;   // + nt*2048 + k0*32
    const unsigned short* wbl  = WTlo + lq*128 + lh*8;

    f32x4 acc[8];
    #pragma unroll
    for (int i = 0; i < 8; i++){
        #pragma unroll
        for (int e = 0; e < 4; e++) acc[i][e] = 0.f;
    }

    if (isbf){
        #pragma unroll
        for (int k0 = 0; k0 < 4; k0++){
            short8 ah = *reinterpret_cast<const short8*>(arow + k0*32);
            #pragma unroll
            for (int nt = 0; nt < 8; nt++){
                short8 bh = *reinterpret_cast<const short8*>(wbh + nt*2048 + k0*32);
                acc[nt] = __builtin_amdgcn_mfma_f32_16x16x32_bf16(ah, bh, acc[nt], 0, 0, 0);
            }
        }
    } else {
        #pragma unroll
        for (int k0 = 0; k0 < 4; k0++){
            short8 ah = *reinterpret_cast<const short8*>(arow + k0*32);
            short8 al = *reinterpret_cast<const short8*>(lrow + k0*32);
            #pragma unroll
            for (int nt = 0; nt < 8; nt++){
                short8 bh = *reinterpret_cast<const short8*>(wbh + nt*2048 + k0*32);
                short8 bl = *reinterpret_cast<const short8*>(wbl + nt*2048 + k0*32);
                acc[nt] = __builtin_amdgcn_mfma_f32_16x16x32_bf16(ah, bh, acc[nt], 0, 0, 0);
                acc[nt] = __builtin_amdgcn_mfma_f32_16x16x32_bf16(al, bh, acc[nt], 0, 0, 0);
                acc[nt] = __builtin_amdgcn_mfma_f32_16x16x32_bf16(ah, bl, acc[nt], 0, 0, 0);
            }
        }
    }

    #pragma unroll
    for (int nt = 0; nt < 8; nt++){
        #pragma unroll
        for (int i = 0; i < 4; i++){
            int row = r0 + wv*16 + lh*4 + i;
            if (row < N) Y[(size_t)row*128 + nt*16 + lq] = __float2half(acc[nt][i]);
        }
    }
}

// ---------- aggregation: one wave per dst row (full-wave R0 structure).
// XW fp16: one row = 256B = 64 lanes x 4B -> one VMEM instr per edge; 8 edges in flight. ----------
__global__ __launch_bounds__(256) void agg_kernel(const unsigned* __restrict__ XWh, const float* __restrict__ dinv,
                                                  const int* __restrict__ offsets, const int* __restrict__ counts,
                                                  const int* __restrict__ csr, const void* __restrict__ bias,
                                                  void* __restrict__ Hout, const int* __restrict__ flags, int N){
    int wave = threadIdx.x >> 6;
    int lane = threadIdx.x & 63;
    int n = blockIdx.x*4 + wave;
    if (n >= N) return;
    int isbf = flags[1];

    float dn = dinv[n];
    float sw = dn*dn;

    float2 sf = h2f2(XWh[(size_t)n*64 + lane]);   // features 2*lane, 2*lane+1
    float accx = sf.x*sw, accy = sf.y*sw;

    int j0 = offsets[n], cnt = counts[n];
    for (int base = 0; base < cnt; base += 64){
        int m = cnt - base; if (m > 64) m = 64;
        int s_l = 0; float w_l = 0.f;
        if (lane < m){
            int s = csr[j0 + base + lane];
            if ((unsigned)s < (unsigned)N){ s_l = s; w_l = dinv[s]*dn; }
        }
        int j = 0;
        for (; j + 8 <= m; j += 8){
            int   s0 = __shfl(s_l, j),   s1 = __shfl(s_l, j+1), s2 = __shfl(s_l, j+2), s3 = __shfl(s_l, j+3);
            int   s4 = __shfl(s_l, j+4), s5 = __shfl(s_l, j+5), s6 = __shfl(s_l, j+6), s7 = __shfl(s_l, j+7);
            float w0 = __shfl(w_l, j),   w1 = __shfl(w_l, j+1), w2 = __shfl(w_l, j+2), w3 = __shfl(w_l, j+3);
            float w4 = __shfl(w_l, j+4), w5 = __shfl(w_l, j+5), w6 = __shfl(w_l, j+6), w7 = __shfl(w_l, j+7);
            unsigned u0 = XWh[(size_t)s0*64 + lane];
            unsigned u1 = XWh[(size_t)s1*64 + lane];
            unsigned u2 = XWh[(size_t)s2*64 + lane];
            unsigned u3 = XWh[(size_t)s3*64 + lane];
            unsigned u4 = XWh[(size_t)s4*64 + lane];
            unsigned u5 = XWh[(size_t)s5*64 + lane];
            unsigned u6 = XWh[(size_t)s6*64 + lane];
            unsigned u7 = XWh[(size_t)s7*64 + lane];
            float2 f0 = h2f2(u0), f1 = h2f2(u1), f2 = h2f2(u2), f3 = h2f2(u3);
            float2 f4 = h2f2(u4), f5 = h2f2(u5), f6 = h2f2(u6), f7 = h2f2(u7);
            accx += f0.x*w0; accy += f0.y*w0;
            accx += f1.x*w1; accy += f1.y*w1;
            accx += f2.x*w2; accy += f2.y*w2;
            accx += f3.x*w3; accy += f3.y*w3;
            accx += f4.x*w4; accy += f4.y*w4;
            accx += f5.x*w5; accy += f5.y*w5;
            accx += f6.x*w6; accy += f6.y*w6;
            accx += f7.x*w7; accy += f7.y*w7;
        }
        for (; j + 4 <= m; j += 4){
            int   s0 = __shfl(s_l, j),   s1 = __shfl(s_l, j+1), s2 = __shfl(s_l, j+2), s3 = __shfl(s_l, j+3);
            float w0 = __shfl(w_l, j),   w1 = __shfl(w_l, j+1), w2 = __shfl(w_l, j+2), w3 = __shfl(w_l, j+3);
            unsigned u0 = XWh[(size_t)s0*64 + lane];
            unsigned u1 = XWh[(size_t)s1*64 + lane];
            unsigned u2 = XWh[(size_t)s2*64 + lane];
            unsigned u3 = XWh[(size_t)s3*64 + lane];
            float2 f0 = h2f2(u0), f1 = h2f2(u1), f2 = h2f2(u2), f3 = h2f2(u3);
            accx += f0.x*w0; accy += f0.y*w0;
            accx += f1.x*w1; accy += f1.y*w1;
            accx += f2.x*w2; accy += f2.y*w2;
            accx += f3.x*w3; accy += f3.y*w3;
        }
        for (; j < m; ++j){
            int   s = __shfl(s_l, j);
            float w = __shfl(w_l, j);
            float2 f = h2f2(XWh[(size_t)s*64 + lane]);
            accx += f.x*w; accy += f.y*w;
        }
    }

    accx = elu_f(accx + loadf(bias, 2*lane,     isbf));
    accy = elu_f(accy + loadf(bias, 2*lane + 1, isbf));
    if (isbf){
        ushort2 o;
        o.x = f2b(accx); o.y = f2b(accy);
        *(ushort2*)((bf16*)Hout + (size_t)n*128 + lane*2) = o;
    } else {
        *(float2*)((float*)Hout + (size_t)n*128 + lane*2) = make_float2(accx, accy);
    }
}

// ---------- MLP head (only Wm2/bm2 survive the reference's reassignment bug) ----------
__global__ __launch_bounds__(256) void mlp_kernel(void* __restrict__ dout, const void* __restrict__ Wm,
                                                  const void* __restrict__ bm, const int* __restrict__ flags, int N){
    __shared__ float ws_[1280];
    __shared__ __align__(16) float hs[16][136];
    int tid = threadIdx.x;
    int isbf = flags[1];
    for (int i = tid; i < 1280; i += 256) ws_[i] = loadf(Wm, i, isbf);

    int r = tid >> 4, c = tid & 15;
    int row = blockIdx.x*16 + r;
    if (isbf){
        if (row < N){
            float4 v = ((const float4*)dout)[(size_t)row*16 + c];   // 8 bf16
            const unsigned short* u = (const unsigned short*)&v;
            #pragma unroll
            for (int j = 0; j < 8; j++) hs[r][c*8 + j] = b2f(u[j]);
        }
    } else {
        if (row < N){
            float4 v0 = ((const float4*)dout)[(size_t)row*32 + c*2];
            float4 v1 = ((const float4*)dout)[(size_t)row*32 + c*2 + 1];
            *(float4*)&hs[r][c*8]     = v0;
            *(float4*)&hs[r][c*8 + 4] = v1;
        }
    }
    __syncthreads();
    if (row < N && c < 10){
        float acc = 0.f;
        #pragma unroll 8
        for (int k = 0; k < 128; k++) acc += hs[r][k]*ws_[k*10 + c];
        acc += loadf(bm, c, isbf);
        float res = elu_f(acc);
        if (isbf){
            ((bf16*)dout)[(size_t)N*128 + (size_t)row*10 + c] = __float2bfloat16(res);
        } else {
            ((float*)dout)[(size_t)N*128 + (size_t)row*10 + c] = res;
        }
    }
}

static inline char* alignup(char* p, size_t a){ return (char*)(((uintptr_t)p + a - 1) & ~(a - 1)); }

extern "C" void kernel_launch(void* const* d_in, const int* in_sizes, int n_in,
                              void* d_out, int out_size, void* d_ws, size_t ws_size,
                              hipStream_t stream){
    const void* x  = d_in[0];
    const int*  ei = (const int*)d_in[1];
    const void* W[4] = {d_in[2], d_in[4], d_in[6], d_in[8]};
    const void* B[4] = {d_in[3], d_in[5], d_in[7], d_in[9]};
    const void* Wm2 = d_in[12];
    const void* bm2 = d_in[13];

    int N = in_sizes[0] / 128;
    int E = in_sizes[1] / 2;

    char* p = (char*)d_ws;
    int*   flags    = (int*)p;
    int*   raw      = flags + 2;                   p = alignup(p + 4*sizeof(int), 256);
    float* dinv     = (float*)p;                   p = alignup(p + (size_t)N*4, 256);
    int*   counts   = (int*)p;                     p = alignup(p + (size_t)N*4, 256);
    int*   offsets  = (int*)p;                     p = alignup(p + (size_t)N*4, 256);
    int*   cursor   = (int*)p;                     p = alignup(p + (size_t)N*4, 256);
    int*   partial  = (int*)p;                     p = alignup(p + 256*4, 256);
    int*   blockoff = (int*)p;                     p = alignup(p + 256*4, 256);
    int*   csr      = (int*)p;                     p = alignup(p + (size_t)E*4, 256);
    __half* xw      = (__half*)p;                  p = alignup(p + (size_t)N*128*4, 256);  // fp16 used; slot kept fp32-sized
    unsigned short* WThi = (unsigned short*)p;     p = alignup(p + (size_t)4*16384*2, 256);
    unsigned short* WTlo = (unsigned short*)p;     p = alignup(p + (size_t)4*16384*2, 256);

    int nb = (N + 255)/256;   // 196 <= 256: single-block top scan valid

    hipMemsetAsync(flags, 0, 4*sizeof(int), stream);
    detect_part_kernel<<<128, 256, 0, stream>>>((const unsigned*)ei, 2*E, (const unsigned*)x, N*128/2, raw, counts, N);
    finalize_kernel   <<<1, 1, 0, stream>>>(raw, flags);
    wprep_kernel  <<<256, 256, 0, stream>>>(W[0], W[1], W[2], W[3], flags, WThi, WTlo);
    count_kernel  <<<(E + 255)/256, 256, 0, stream>>>(ei, flags, counts, E, N);
    partial_kernel<<<nb, 256, 0, stream>>>(counts, partial, N);
    scanp_kernel  <<<1, 256, 0, stream>>>(partial, blockoff, nb);
    offsets_kernel<<<nb, 256, 0, stream>>>(counts, blockoff, offsets, cursor, dinv, N);
    scatter_kernel<<<(E + 255)/256, 256, 0, stream>>>(ei, flags, cursor, csr, E, N);

    for (int l = 0; l < 4; ++l){
        const void* Xin = (l == 0) ? x : (const void*)d_out;
        gemm_kernel<<<(N + 63)/64, 256, 0, stream>>>(Xin, WThi + (size_t)l*16384, WTlo + (size_t)l*16384, flags, xw, N);
        agg_kernel <<<(N + 3)/4, 256, 0, stream>>>((const unsigned*)xw, dinv, offsets, counts, csr, B[l], d_out, flags, N);
    }
    mlp_kernel<<<((N*16) + 255)/256, 256, 0, stream>>>(d_out, Wm2, bm2, flags, N);
}

// Round 7
// 405.243 us; speedup vs baseline: 1.1444x; 1.1444x over previous
//
#include <hip/hip_runtime.h>
#include <hip/hip_bf16.h>
#include <hip/hip_fp16.h>
#include <math.h>

typedef __hip_bfloat16 bf16;
typedef __attribute__((ext_vector_type(8))) short short8;
typedef __attribute__((ext_vector_type(4))) float f32x4;

__device__ __forceinline__ float elu_f(float x){ return x > 0.f ? x : expm1f(x); }
__device__ __forceinline__ float b2f(unsigned short u){ return __uint_as_float(((unsigned)u) << 16); }
__device__ __forceinline__ unsigned short f2b(float f){ bf16 h = __float2bfloat16(f); return *reinterpret_cast<unsigned short*>(&h); }
__device__ __forceinline__ float2 h2f2(unsigned u){
    __half2 h = *reinterpret_cast<__half2*>(&u);
    return make_float2(__low2float(h), __high2float(h));
}

// dtype flags computed directly from raw[] (finalize_kernel folded away):
// raw[0] = OR of sampled odd words of edge_index (0 => int64 indices)
// raw[1] = count of bf16-looking samples out of 4096
__device__ __forceinline__ int f_is64(const int* raw){ return raw[0] == 0; }
__device__ __forceinline__ int f_isbf(const int* raw){ return raw[1]*2 > 4096; }

__device__ __forceinline__ int load_src(const int* ei, int e, int E, int is64){
    return is64 ? ei[2*e] : ei[e];
}
__device__ __forceinline__ int load_dst(const int* ei, int e, int E, int is64){
    return is64 ? ei[2*(E + e)] : ei[E + e];
}
__device__ __forceinline__ float loadf(const void* base, size_t idx, int isbf){
    return isbf ? __bfloat162float(((const bf16*)base)[idx]) : ((const float*)base)[idx];
}

// ---------- dtype detection (parallel) + counts zeroing (folded) ----------
__global__ __launch_bounds__(256) void detect_part_kernel(const unsigned* __restrict__ ei_u, int twoE_words,
                                                          const unsigned* __restrict__ x_u, int min_xwords,
                                                          int* __restrict__ raw,
                                                          int* __restrict__ counts, int N){
    __shared__ int sd[256];
    __shared__ int sc[256];
    int tid = threadIdx.x;
    int gid = blockIdx.x*256 + tid;
    long long pairs = twoE_words/2;

    for (int i2 = gid; i2 < N; i2 += 32768) counts[i2] = 0;

    int orv = 0;
    if (gid < 16384 && pairs > 0){
        long long idx = ((long long)gid * pairs) / 16384;
        long long w = 2*idx + 1;
        if (w < twoE_words) orv = (int)ei_u[w];
    }
    int cnt = 0;
    int s = gid - 16384;
    if (s >= 0 && s < 4096){
        long long idx = ((long long)s * min_xwords) / 4096;
        if (idx < min_xwords){
            unsigned e = (x_u[idx] >> 7) & 0xFFu;
            cnt = (e >= 96u && e <= 160u) ? 1 : 0;
        }
    }
    sd[tid] = orv; sc[tid] = cnt;
    __syncthreads();
    #pragma unroll
    for (int off = 128; off > 0; off >>= 1){
        if (tid < off){ sd[tid] |= sd[tid+off]; sc[tid] += sc[tid+off]; }
        __syncthreads();
    }
    if (tid == 0){
        if (sd[0]) atomicOr(&raw[0], sd[0]);
        if (sc[0]) atomicAdd(&raw[1], sc[0]);
    }
}

// ---------- W prep: W^T split into bf16 hi/lo ----------
__global__ __launch_bounds__(256) void wprep_kernel(const void* __restrict__ W0, const void* __restrict__ W1,
                                                    const void* __restrict__ W2, const void* __restrict__ W3,
                                                    const int* __restrict__ raw,
                                                    unsigned short* __restrict__ WThi, unsigned short* __restrict__ WTlo){
    int l = blockIdx.x >> 6;
    const void* Wl = l == 0 ? W0 : l == 1 ? W1 : l == 2 ? W2 : W3;
    int isbf = f_isbf(raw);
    int o = (blockIdx.x & 63)*256 + threadIdx.x;   // o = c*128 + k
    int c = o >> 7, k = o & 127;
    unsigned short hi, lo;
    if (isbf){
        hi = ((const unsigned short*)Wl)[k*128 + c]; lo = 0;
    } else {
        float w = ((const float*)Wl)[k*128 + c];
        hi = f2b(w);
        lo = f2b(w - b2f(hi));
    }
    WThi[(size_t)l*16384 + o] = hi;
    WTlo[(size_t)l*16384 + o] = lo;
}

// ---------- CSR build ----------
__global__ void count_kernel(const int* __restrict__ ei, const int* __restrict__ raw,
                             int* __restrict__ counts, int E, int N){
    int e = blockIdx.x*256 + threadIdx.x;
    if (e < E){
        int d = load_dst(ei, e, E, f_is64(raw));
        if ((unsigned)d < (unsigned)N) atomicAdd(&counts[d], 1);
    }
}

__global__ void partial_kernel(const int* __restrict__ counts, int* __restrict__ partial, int N){
    __shared__ int sd[256];
    int tid = threadIdx.x;
    int i = blockIdx.x*256 + tid;
    sd[tid] = (i < N) ? counts[i] : 0;
    __syncthreads();
    #pragma unroll
    for (int off = 128; off > 0; off >>= 1){
        if (tid < off) sd[tid] += sd[tid+off];
        __syncthreads();
    }
    if (tid == 0) partial[blockIdx.x] = sd[0];
}

// offsets + cursor + dinv, with INLINE top-level scan (scanp_kernel folded away):
// each block strided-sums partial[0..blockIdx.x) itself (<= nb ints, L2-hot).
__global__ void offsets_kernel(const int* __restrict__ counts, const int* __restrict__ partial,
                               int* __restrict__ offsets, int* __restrict__ cursor,
                               float* __restrict__ dinv, int N){
    __shared__ int sd[256];
    __shared__ int sbase;
    int tid = threadIdx.x;

    int acc = 0;
    for (int i = tid; i < (int)blockIdx.x; i += 256) acc += partial[i];
    sd[tid] = acc;
    __syncthreads();
    #pragma unroll
    for (int off = 128; off > 0; off >>= 1){
        if (tid < off) sd[tid] += sd[tid+off];
        __syncthreads();
    }
    if (tid == 0) sbase = sd[0];
    __syncthreads();

    int i = blockIdx.x*256 + tid;
    int v = (i < N) ? counts[i] : 0;
    sd[tid] = v;
    __syncthreads();
    #pragma unroll
    for (int off = 1; off < 256; off <<= 1){
        int t = (tid >= off) ? sd[tid-off] : 0;
        __syncthreads();
        sd[tid] += t;
        __syncthreads();
    }
    if (i < N){
        int o = sbase + sd[tid] - v;
        offsets[i] = o;
        cursor[i]  = o;
        double d = (double)(v + 1);
        if (d < 1.0) d = 1.0;
        dinv[i] = (float)(1.0 / sqrt(d));
    }
}

__global__ void scatter_kernel(const int* __restrict__ ei, const int* __restrict__ raw,
                               int* __restrict__ cursor, int* __restrict__ csr, int E, int N){
    int e = blockIdx.x*256 + threadIdx.x;
    if (e < E){
        int is64 = f_is64(raw);
        int d = load_dst(ei, e, E, is64);
        int s = load_src(ei, e, E, is64);
        if ((unsigned)d < (unsigned)N){
            int pos = atomicAdd(&cursor[d], 1);
            if ((unsigned)pos < (unsigned)E) csr[pos] = s;
        }
    }
}

// ---------- GEMM (proven R4 form): XW = X @ W on matrix cores, fp16 out; W chunk-staged in LDS.
// fp32 path: bf16x2 split (hi/lo), 3 MFMA passes. bf16 path: single pass.
// Fragment recipe (verified m92/m97): row-major A + B^T; lane reads row (lane&15),
// 8 contiguous k at 8*(lane>>4); C/D: col=lane&15, row=4*(lane>>4)+reg.
__global__ __launch_bounds__(256) void gemm_kernel(const void* __restrict__ X,
                                                   const unsigned short* __restrict__ WThi,
                                                   const unsigned short* __restrict__ WTlo,
                                                   const int* __restrict__ raw,
                                                   __half* __restrict__ Y, int N){
    __shared__ __align__(16) unsigned short xhi[64*136];
    __shared__ __align__(16) unsigned short xlo[64*136];
    __shared__ __align__(16) unsigned short bh[128*40];
    __shared__ __align__(16) unsigned short bl[128*40];
    int tid = threadIdx.x;
    int r0 = blockIdx.x*64;
    int isbf = f_isbf(raw);

    if (isbf){
        for (int i = tid; i < 64*16; i += 256){
            int r = i >> 4, sg = i & 15;
            float4 v = make_float4(0.f,0.f,0.f,0.f);
            if (r0 + r < N) v = ((const float4*)X)[(size_t)(r0+r)*16 + sg];
            *(float4*)&xhi[r*136 + sg*8] = v;
        }
    } else {
        for (int i = tid; i < 64*32; i += 256){
            int r = i >> 5, f4 = i & 31;
            float4 v = make_float4(0.f,0.f,0.f,0.f);
            if (r0 + r < N) v = ((const float4*)X)[(size_t)(r0+r)*32 + f4];
            ushort4 hv, lv;
            hv.x = f2b(v.x); lv.x = f2b(v.x - b2f(hv.x));
            hv.y = f2b(v.y); lv.y = f2b(v.y - b2f(hv.y));
            hv.z = f2b(v.z); lv.z = f2b(v.z - b2f(hv.z));
            hv.w = f2b(v.w); lv.w = f2b(v.w - b2f(hv.w));
            *(ushort4*)&xhi[r*136 + f4*4] = hv;
            *(ushort4*)&xlo[r*136 + f4*4] = lv;
        }
    }

    int wv = tid >> 6, lane = tid & 63;
    int lq = lane & 15, lh = lane >> 4;

    f32x4 acc[8];
    #pragma unroll
    for (int i = 0; i < 8; i++){
        #pragma unroll
        for (int e = 0; e < 4; e++) acc[i][e] = 0.f;
    }

    for (int k0 = 0; k0 < 4; k0++){
        __syncthreads();   // protect b-chunk from previous iteration's readers; k0=0: cover x staging
        for (int i = tid; i < 512; i += 256){
            int rr = i >> 2, sg = i & 3;
            *(float4*)&bh[rr*40 + sg*8] = *(const float4*)&WThi[rr*128 + k0*32 + sg*8];
        }
        if (!isbf){
            for (int i = tid; i < 512; i += 256){
                int rr = i >> 2, sg = i & 3;
                *(float4*)&bl[rr*40 + sg*8] = *(const float4*)&WTlo[rr*128 + k0*32 + sg*8];
            }
        }
        __syncthreads();

        short8 ah = *reinterpret_cast<const short8*>(&xhi[(wv*16 + lq)*136 + k0*32 + lh*8]);
        if (isbf){
            #pragma unroll
            for (int nt = 0; nt < 8; nt++){
                short8 bhf = *reinterpret_cast<const short8*>(&bh[(nt*16 + lq)*40 + lh*8]);
                acc[nt] = __builtin_amdgcn_mfma_f32_16x16x32_bf16(ah, bhf, acc[nt], 0, 0, 0);
            }
        } else {
            short8 al = *reinterpret_cast<const short8*>(&xlo[(wv*16 + lq)*136 + k0*32 + lh*8]);
            #pragma unroll
            for (int nt = 0; nt < 8; nt++){
                short8 bhf = *reinterpret_cast<const short8*>(&bh[(nt*16 + lq)*40 + lh*8]);
                short8 blf = *reinterpret_cast<const short8*>(&bl[(nt*16 + lq)*40 + lh*8]);
                acc[nt] = __builtin_amdgcn_mfma_f32_16x16x32_bf16(ah, bhf, acc[nt], 0, 0, 0);
                acc[nt] = __builtin_amdgcn_mfma_f32_16x16x32_bf16(al, bhf, acc[nt], 0, 0, 0);
                acc[nt] = __builtin_amdgcn_mfma_f32_16x16x32_bf16(ah, blf, acc[nt], 0, 0, 0);
            }
        }
    }

    #pragma unroll
    for (int nt = 0; nt < 8; nt++){
        #pragma unroll
        for (int i = 0; i < 4; i++){
            int row = r0 + wv*16 + lh*4 + i;
            if (row < N) Y[(size_t)row*128 + nt*16 + lq] = __float2half(acc[nt][i]);
        }
    }
}

// ---------- aggregation (proven R4 form): one wave per dst row; fp16 XW row = 256B =
// 64 lanes x 4B -> one VMEM instr per edge, 4 gathers in flight ----------
__global__ __launch_bounds__(256) void agg_kernel(const unsigned* __restrict__ XWh, const float* __restrict__ dinv,
                                                  const int* __restrict__ offsets, const int* __restrict__ counts,
                                                  const int* __restrict__ csr, const void* __restrict__ bias,
                                                  void* __restrict__ Hout, const int* __restrict__ raw, int N){
    int wave = threadIdx.x >> 6;
    int lane = threadIdx.x & 63;
    int n = blockIdx.x*4 + wave;
    if (n >= N) return;
    int isbf = f_isbf(raw);

    float dn = dinv[n];
    float sw = dn*dn;

    float2 sf = h2f2(XWh[(size_t)n*64 + lane]);   // features 2*lane, 2*lane+1
    float accx = sf.x*sw, accy = sf.y*sw;

    int j0 = offsets[n], cnt = counts[n];
    for (int base = 0; base < cnt; base += 64){
        int m = cnt - base; if (m > 64) m = 64;
        int s_l = 0; float w_l = 0.f;
        if (lane < m){
            int s = csr[j0 + base + lane];
            if ((unsigned)s < (unsigned)N){ s_l = s; w_l = dinv[s]*dn; }
        }
        int j = 0;
        for (; j + 4 <= m; j += 4){
            int   s0 = __shfl(s_l, j),   s1 = __shfl(s_l, j+1), s2 = __shfl(s_l, j+2), s3 = __shfl(s_l, j+3);
            float w0 = __shfl(w_l, j),   w1 = __shfl(w_l, j+1), w2 = __shfl(w_l, j+2), w3 = __shfl(w_l, j+3);
            unsigned u0 = XWh[(size_t)s0*64 + lane];
            unsigned u1 = XWh[(size_t)s1*64 + lane];
            unsigned u2 = XWh[(size_t)s2*64 + lane];
            unsigned u3 = XWh[(size_t)s3*64 + lane];
            float2 f0 = h2f2(u0), f1 = h2f2(u1), f2 = h2f2(u2), f3 = h2f2(u3);
            accx += f0.x*w0; accy += f0.y*w0;
            accx += f1.x*w1; accy += f1.y*w1;
            accx += f2.x*w2; accy += f2.y*w2;
            accx += f3.x*w3; accy += f3.y*w3;
        }
        for (; j < m; ++j){
            int   s = __shfl(s_l, j);
            float w = __shfl(w_l, j);
            float2 f = h2f2(XWh[(size_t)s*64 + lane]);
            accx += f.x*w; accy += f.y*w;
        }
    }

    accx = elu_f(accx + loadf(bias, 2*lane,     isbf));
    accy = elu_f(accy + loadf(bias, 2*lane + 1, isbf));
    if (isbf){
        ushort2 o;
        o.x = f2b(accx); o.y = f2b(accy);
        *(ushort2*)((bf16*)Hout + (size_t)n*128 + lane*2) = o;
    } else {
        *(float2*)((float*)Hout + (size_t)n*128 + lane*2) = make_float2(accx, accy);
    }
}

// ---------- MLP head (only Wm2/bm2 survive the reference's reassignment bug) ----------
__global__ __launch_bounds__(256) void mlp_kernel(void* __restrict__ dout, const void* __restrict__ Wm,
                                                  const void* __restrict__ bm, const int* __restrict__ raw, int N){
    __shared__ float ws_[1280];
    __shared__ __align__(16) float hs[16][136];
    int tid = threadIdx.x;
    int isbf = f_isbf(raw);
    for (int i = tid; i < 1280; i += 256) ws_[i] = loadf(Wm, i, isbf);

    int r = tid >> 4, c = tid & 15;
    int row = blockIdx.x*16 + r;
    if (isbf){
        if (row < N){
            float4 v = ((const float4*)dout)[(size_t)row*16 + c];   // 8 bf16
            const unsigned short* u = (const unsigned short*)&v;
            #pragma unroll
            for (int j = 0; j < 8; j++) hs[r][c*8 + j] = b2f(u[j]);
        }
    } else {
        if (row < N){
            float4 v0 = ((const float4*)dout)[(size_t)row*32 + c*2];
            float4 v1 = ((const float4*)dout)[(size_t)row*32 + c*2 + 1];
            *(float4*)&hs[r][c*8]     = v0;
            *(float4*)&hs[r][c*8 + 4] = v1;
        }
    }
    __syncthreads();
    if (row < N && c < 10){
        float acc = 0.f;
        #pragma unroll 8
        for (int k = 0; k < 128; k++) acc += hs[r][k]*ws_[k*10 + c];
        acc += loadf(bm, c, isbf);
        float res = elu_f(acc);
        if (isbf){
            ((bf16*)dout)[(size_t)N*128 + (size_t)row*10 + c] = __float2bfloat16(res);
        } else {
            ((float*)dout)[(size_t)N*128 + (size_t)row*10 + c] = res;
        }
    }
}

static inline char* alignup(char* p, size_t a){ return (char*)(((uintptr_t)p + a - 1) & ~(a - 1)); }

extern "C" void kernel_launch(void* const* d_in, const int* in_sizes, int n_in,
                              void* d_out, int out_size, void* d_ws, size_t ws_size,
                              hipStream_t stream){
    const void* x  = d_in[0];
    const int*  ei = (const int*)d_in[1];
    const void* W[4] = {d_in[2], d_in[4], d_in[6], d_in[8]};
    const void* B[4] = {d_in[3], d_in[5], d_in[7], d_in[9]};
    const void* Wm2 = d_in[12];
    const void* bm2 = d_in[13];

    int N = in_sizes[0] / 128;
    int E = in_sizes[1] / 2;

    char* p = (char*)d_ws;
    int*   raw      = (int*)p;                     p = alignup(p + 4*sizeof(int), 256);
    float* dinv     = (float*)p;                   p = alignup(p + (size_t)N*4, 256);
    int*   counts   = (int*)p;                     p = alignup(p + (size_t)N*4, 256);
    int*   offsets  = (int*)p;                     p = alignup(p + (size_t)N*4, 256);
    int*   cursor   = (int*)p;                     p = alignup(p + (size_t)N*4, 256);
    int*   partial  = (int*)p;                     p = alignup(p + 256*4, 256);
    int*   csr      = (int*)p;                     p = alignup(p + (size_t)E*4, 256);
    __half* xw      = (__half*)p;                  p = alignup(p + (size_t)N*128*4, 256);  // fp16 used; slot kept fp32-sized
    unsigned short* WThi = (unsigned short*)p;     p = alignup(p + (size_t)4*16384*2, 256);
    unsigned short* WTlo = (unsigned short*)p;     p = alignup(p + (size_t)4*16384*2, 256);

    int nb = (N + 255)/256;

    hipMemsetAsync(raw, 0, 4*sizeof(int), stream);
    detect_part_kernel<<<128, 256, 0, stream>>>((const unsigned*)ei, 2*E, (const unsigned*)x, N*128/2, raw, counts, N);
    wprep_kernel  <<<256, 256, 0, stream>>>(W[0], W[1], W[2], W[3], raw, WThi, WTlo);
    count_kernel  <<<(E + 255)/256, 256, 0, stream>>>(ei, raw, counts, E, N);
    partial_kernel<<<nb, 256, 0, stream>>>(counts, partial, N);
    offsets_kernel<<<nb, 256, 0, stream>>>(counts, partial, offsets, cursor, dinv, N);
    scatter_kernel<<<(E + 255)/256, 256, 0, stream>>>(ei, raw, cursor, csr, E, N);

    for (int l = 0; l < 4; ++l){
        const void* Xin = (l == 0) ? x : (const void*)d_out;
        gemm_kernel<<<(N + 63)/64, 256, 0, stream>>>(Xin, WThi + (size_t)l*16384, WTlo + (size_t)l*16384, raw, xw, N);
        agg_kernel <<<(N + 3)/4, 256, 0, stream>>>((const unsigned*)xw, dinv, offsets, counts, csr, B[l], d_out, raw, N);
    }
    mlp_kernel<<<((N*16) + 255)/256, 256, 0, stream>>>(d_out, Wm2, bm2, raw, N);
}